// Round 10
// baseline (273.594 us; speedup 1.0000x reference)
//
#include <hip/hip_runtime.h>

// Problem constants (match reference)
#define K_     1056
#define N_     2112
#define M_     1056   // N - K
#define E_     6336   // M * 6
#define NIE_   5280   // M * 5 info-side edges (the only BP state)
#define CAP_   6336   // NIE_ + K worst-case padding (stride = d|1)
#define DV_    5
#define ROW_   6      // edge 6m+5 is the parity VN K+m
#define NSYM_  528
#define NITER_ 20
#define BATCH_ 1024

#define LOG2E_ 1.4426950408889634f
#define AVLO_  (1e-6f * LOG2E_)          // |v2c| floor, bits units
#define AVHI_  (20.0f * LOG2E_)          // |v2c| cap,  bits units
#define QC_    0.99999988f               // tanh-domain cap (unchanged)

// stride(d) = d | 1 : odd d -> d (no pad), even d -> d+1. Always ODD ->
// coprime with the 32 LDS banks -> Phase A's wave-uniform-stride segment
// reads are conflict-free. Total extent <= NIE_ + K_ = 6336.
__device__ __forceinline__ int seg_stride(int d) { return d | 1; }

// -------------------------------------------------------------------------
// Single kernel, one block per codeword. Whole pipeline in base-2 LLR
// domain after demap (LLR_hat = LLR * log2e): v_exp_f32/v_log_f32 are
// natively 2^x/log2(x), so tanh and the CN message need NO base-conversion
// multiplies. Hard decisions are invariant under the positive scaling.
//
// LDS (~30 KB -> 5 blocks/CU):
//   s_mem[CAP]  : staging (N floats: bits -> demapped LLR_hat) with build
//                 int scratch packed at [N..CAP); then the c2v message
//                 array in odd-stride padded VN-major segments
//   s_marg[K]   : slot-indexed per-iteration marginals
//
// Structure exploited: H = [A | I].
//   * Parity VN (deg 1): v2c == channel LLR -> per-check constant t5;
//     CN->parity messages never computed.
//   * Info VNs counting-sorted by degree -> wave-uniform Phase A trips;
//     scan-free segment bases from 32-bin histogram arithmetic.
//   * Old c2v in registers (c2vr); fmed3 clamps (bit-identical to min/max).
//   * Atomic build order only permutes float accumulation order —
//     validated order-independent in R4-R8 (absmax 0).
//
// CN math (product form, prefix/suffix partial products, bits domain):
//   t = copysign((1-2^-av)/(1+2^-av), v2c);  q_j = t5 * prod_{i!=j} t_i
//   q = med3(q, -QC, QC);  r = log2((1+q)/(1-q))
// -------------------------------------------------------------------------
__global__ __launch_bounds__(256, 5) void link_kernel(
    const int*   __restrict__ bits,      // [B,K]
    const int*   __restrict__ a_idx,     // [M,DV]
    const float* __restrict__ points_re, // [16]
    const float* __restrict__ points_im, // [16]
    const float* __restrict__ noise_re,  // [B,NSYM]
    const float* __restrict__ noise_im,  // [B,NSYM]
    const float* __restrict__ ebno_db,   // [1]
    const int*   __restrict__ edge_vn,   // [E]
    float*       __restrict__ out)       // [2,B,K]
{
#pragma clang fp contract(off)
    const int b   = blockIdx.x;
    const int tid = threadIdx.x;

    __shared__ float s_mem[CAP_];
    __shared__ float s_marg[K_];
    __shared__ float s_pre[16];
    __shared__ float s_pim[16];
    __shared__ int   s_hist[32];
    __shared__ int   s_binStart[32];
    __shared__ int   s_binBase[32];

    // build scratch aliases the tail of s_mem (N_ + 4*K_ == CAP_ exactly)
    int* sc        = (int*)(s_mem + N_);
    int* s_deg     = sc;                 // [K] degree
    int* s_perm    = sc + K_;            // [K] slot -> v | deg<<16
    int* s_offslot = sc + 2 * K_;        // [K] v -> base | slot<<16
    int* s_cnt     = sc + 3 * K_;        // [K] edge-fill cursors

    if (tid < 16) {
        s_pre[tid] = points_re[tid];
        s_pim[tid] = points_im[tid];
    }
    if (tid < 32) s_hist[tid] = 0;

    const float eb    = ebno_db[0];
    const float no    = 1.0f / ((powf(10.0f, eb / 10.0f) * 0.5f) * 4.0f);
    const float sigma = sqrtf(no / 2.0f);

    // ---- stage info bits (0/1 floats); output0 = bits.astype(f32) ----
    for (int i = tid; i < K_; i += 256) {
        int v = bits[b * K_ + i];
        s_mem[i] = (float)v;
        out[b * K_ + i] = (float)v;
    }
    __syncthreads();

    // ---- parity: XOR of DV gathered info bits; zero build counters ----
    for (int m = tid; m < M_; m += 256) {
        float acc = 0.0f;
        #pragma unroll
        for (int d = 0; d < DV_; ++d) acc += s_mem[a_idx[m * DV_ + d]];
        s_mem[K_ + m] = (float)(((int)acc) & 1);
    }
    for (int v = tid; v < K_; v += 256) { s_deg[v] = 0; s_cnt[v] = 0; }
    __syncthreads();

    // ---- QAM + AWGN + exact APP demap (stores LLR * log2e) ----
    // ---- overlapped: VN degree count (disjoint LDS region)       ----
    for (int s = tid; s < NSYM_; s += 256) {
        int c0 = (int)s_mem[4 * s + 0];
        int c1 = (int)s_mem[4 * s + 1];
        int c2 = (int)s_mem[4 * s + 2];
        int c3 = (int)s_mem[4 * s + 3];
        int sym = c0 * 8 + c1 * 4 + c2 * 2 + c3;
        float yre = s_pre[sym] + sigma * noise_re[b * NSYM_ + s];
        float yim = s_pim[sym] + sigma * noise_im[b * NSYM_ + s];
        float lg[16];
        #pragma unroll
        for (int p = 0; p < 16; ++p) {
            float dre  = yre - s_pre[p];
            float dim_ = yim - s_pim[p];
            float d2   = dre * dre + dim_ * dim_;
            lg[p] = -d2 / no;
        }
        float llr4[4];
        #pragma unroll
        for (int j = 0; j < 4; ++j) {
            float m0 = -1e30f, m1 = -1e30f;
            #pragma unroll
            for (int p = 0; p < 16; ++p) {
                if (((p >> (3 - j)) & 1) == 0) m0 = fmaxf(m0, lg[p]);
                else                           m1 = fmaxf(m1, lg[p]);
            }
            float sum0 = 0.0f, sum1 = 0.0f;
            #pragma unroll
            for (int p = 0; p < 16; ++p) {
                if (((p >> (3 - j)) & 1) == 0) sum0 += __expf(lg[p] - m0);
                else                           sum1 += __expf(lg[p] - m1);
            }
            llr4[j] = (m0 + __logf(sum0)) - (m1 + __logf(sum1));
        }
        s_mem[4 * s + 0] = llr4[0] * LOG2E_;
        s_mem[4 * s + 1] = llr4[1] * LOG2E_;
        s_mem[4 * s + 2] = llr4[2] * LOG2E_;
        s_mem[4 * s + 3] = llr4[3] * LOG2E_;
    }
    for (int idx = tid; idx < NIE_; idx += 256) {
        int m = idx / 5, j = idx - m * 5;
        atomicAdd(&s_deg[edge_vn[m * ROW_ + j]], 1);
    }
    __syncthreads();

    // ---- degree histogram -> arithmetic segment bases (scan-free) ----
    for (int v = tid; v < K_; v += 256) atomicAdd(&s_hist[s_deg[v] & 31], 1);
    __syncthreads();
    if (tid == 0) {
        int accS = 0, accB = 0;
        for (int d = 0; d < 32; ++d) {
            int c = s_hist[d];
            s_binStart[d] = accS;
            s_binBase[d]  = accB;
            s_hist[d]     = accS;        // reuse as sort cursor
            accS += c;
            accB += c * seg_stride(d);
        }
    }
    __syncthreads();
    for (int v = tid; v < K_; v += 256) {   // counting sort by degree
        int d    = s_deg[v];
        int slot = atomicAdd(&s_hist[d & 31], 1);
        int base = s_binBase[d] + (slot - s_binStart[d]) * seg_stride(d);
        s_perm[slot]  = v | (d << 16);
        s_offslot[v]  = base | (slot << 16);
    }
    __syncthreads();

    // ---- capture iteration-invariant state in registers ----
    int      pv[5];                      // slot -> VN id
    unsigned od[5];                      // base | deg<<16
    float    lr[5];                      // channel LLR_hat of owned VN
    #pragma unroll
    for (int k = 0; k < 5; ++k) {
        int s = tid + 256 * k;
        if (s < K_) {
            int w = s_perm[s];
            int v = w & 0xFFFF;
            int d = w >> 16;
            int base = s_binBase[d] + (s - s_binStart[d]) * seg_stride(d);
            pv[k] = v;
            od[k] = (unsigned)base | ((unsigned)d << 16);
            lr[k] = s_mem[v];
        } else { pv[k] = 0; od[k] = 0; lr[k] = 0.0f; }
    }
    float    t5[5];
    unsigned vnp[5][5];                  // slot | pos<<16
    float    c2vr[5][5];                 // previous c2v (registers)
    #pragma unroll
    for (int kk = 0; kk < 5; ++kk) {
        int m = tid + 256 * kk;
        if (m < M_) {
            #pragma unroll
            for (int j = 0; j < 5; ++j) {
                int v = edge_vn[m * ROW_ + j];
                int r = atomicAdd(&s_cnt[v], 1);
                int w = s_offslot[v];
                vnp[kk][j]  = (unsigned)(w >> 16) | ((unsigned)((w & 0xFFFF) + r) << 16);
                c2vr[kk][j] = 0.0f;
            }
            float lrP = s_mem[K_ + m];
            float av  = __builtin_amdgcn_fmed3f(fabsf(lrP), AVLO_, AVHI_);
            float e   = exp2f(-av);
            float tm  = __fdividef(1.0f - e, 1.0f + e);
            t5[kk] = copysignf(tm, lrP);
        } else { t5[kk] = 0.0f; }
    }
    __syncthreads();
    // scratch fully consumed -> become the message array
    for (int i = tid; i < CAP_; i += 256) s_mem[i] = 0.0f;
    __syncthreads();

    // ---- sum-product BP, flooding (all quantities in bits domain) ----
    for (int it = 0; it < NITER_; ++it) {
        // Phase A: slot-indexed marginals; paired reads -> ds_read2_b32
        #pragma unroll
        for (int k = 0; k < 5; ++k) {
            int s = tid + 256 * k;
            if (s < K_) {
                int base = (int)(od[k] & 0xFFFFu);
                int dg   = (int)(od[k] >> 16);
                float mg = lr[k];
                int d = 0;
                for (; d + 1 < dg; d += 2) {
                    mg += s_mem[base + d];
                    mg += s_mem[base + d + 1];
                }
                if (d < dg) mg += s_mem[base + d];
                s_marg[s] = mg;
            }
        }
        __syncthreads();
        // Phase B: CN update, prefix/suffix products; old c2v in registers
        #pragma unroll
        for (int kk = 0; kk < 5; ++kk) {
            int m = tid + 256 * kk;
            if (m < M_) {
                float tj[5];
                #pragma unroll
                for (int j = 0; j < 5; ++j) {
                    unsigned w = vnp[kk][j];
                    float v2c = s_marg[w & 0xFFFFu] - c2vr[kk][j];
                    float av  = __builtin_amdgcn_fmed3f(fabsf(v2c), AVLO_, AVHI_);
                    float e   = exp2f(-av);
                    float tm  = __fdividef(1.0f - e, 1.0f + e);
                    tj[j] = copysignf(tm, v2c);
                }
                float qv[5];
                float pr = t5[kk];
                #pragma unroll
                for (int j = 0; j < 5; ++j) { qv[j] = pr; pr *= tj[j]; }
                float sf = 1.0f;
                #pragma unroll
                for (int j = 4; j >= 0; --j) { qv[j] *= sf; sf *= tj[j]; }
                #pragma unroll
                for (int j = 0; j < 5; ++j) {
                    float q = __builtin_amdgcn_fmed3f(qv[j], -QC_, QC_);
                    float r = log2f(__fdividef(1.0f + q, 1.0f - q));
                    s_mem[vnp[kk][j] >> 16] = r;
                    c2vr[kk][j] = r;
                }
            }
        }
        __syncthreads();
    }

    // ---- final marginal + hard decision on info VNs ----
    #pragma unroll
    for (int k = 0; k < 5; ++k) {
        int s = tid + 256 * k;
        if (s < K_) {
            int base = (int)(od[k] & 0xFFFFu);
            int dg   = (int)(od[k] >> 16);
            float mg = lr[k];
            int d = 0;
            for (; d + 1 < dg; d += 2) {
                mg += s_mem[base + d];
                mg += s_mem[base + d + 1];
            }
            if (d < dg) mg += s_mem[base + d];
            out[(size_t)BATCH_ * K_ + b * K_ + pv[k]] = (mg < 0.0f) ? 1.0f : 0.0f;
        }
    }
}

extern "C" void kernel_launch(void* const* d_in, const int* in_sizes, int n_in,
                              void* d_out, int out_size, void* d_ws, size_t ws_size,
                              hipStream_t stream) {
    const int*   bits    = (const int*)  d_in[0];
    const int*   a_idx   = (const int*)  d_in[1];
    // d_in[2] = edge_cn (implicit: contiguous groups of 6) — unused
    const int*   edge_vn = (const int*)  d_in[3];
    const float* pre     = (const float*)d_in[4];
    const float* pim     = (const float*)d_in[5];
    const float* nre     = (const float*)d_in[6];
    const float* nim     = (const float*)d_in[7];
    const float* ebno    = (const float*)d_in[8];

    link_kernel<<<BATCH_, 256, 0, stream>>>(bits, a_idx, pre, pim, nre, nim,
                                            ebno, edge_vn, (float*)d_out);
}

// Round 11
// 258.632 us; speedup vs baseline: 1.0579x; 1.0579x over previous
//
#include <hip/hip_runtime.h>

// Problem constants (match reference)
#define K_     1056
#define N_     2112
#define M_     1056   // N - K
#define E_     6336   // M * 6
#define NIE_   5280   // M * 5 info-side edges (the only BP state)
#define CAP_   6336   // NIE_ + K worst-case padding (stride = d|1)
#define DV_    5
#define ROW_   6      // edge 6m+5 is the parity VN K+m
#define NSYM_  528
#define NITER_ 20
#define BATCH_ 1024

#define LOG2E_ 1.4426950408889634f
#define AVLO_  (1e-6f * LOG2E_)          // |v2c| floor, bits units
#define AVHI_  (20.0f * LOG2E_)          // |v2c| cap,  bits units
#define QC_    0.99999988f               // tanh-domain cap (unchanged)

// stride(d) = d | 1 : odd d -> d (no pad), even d -> d+1. Always ODD ->
// coprime with the 32 LDS banks -> Phase A's wave-uniform-stride segment
// reads are conflict-free. Total extent <= NIE_ + K_ = 6336.
__device__ __forceinline__ int seg_stride(int d) { return d | 1; }

// -------------------------------------------------------------------------
// Single kernel, one block per codeword. Whole pipeline in base-2 LLR
// domain after demap (LLR_hat = LLR * log2e): v_exp_f32/v_log_f32 are
// natively 2^x/log2(x), so tanh and the CN message need NO base-conversion
// multiplies. Hard decisions are invariant under the positive scaling.
//
// LDS (~30 KB -> 5 blocks/CU):
//   s_mem[CAP]  : staging (N floats: bits -> demapped LLR_hat) with build
//                 int scratch packed at [N..CAP); then the c2v message
//                 array in odd-stride padded VN-major segments
//   s_marg[K]   : slot-indexed per-iteration marginals
//
// NOTE __launch_bounds__(256, 4): the (256,5) variant (R9) made the
// allocator collapse to 48 VGPRs and spill ~34 MB/dispatch to scratch
// (FETCH 15 MB, WRITE 32 MB, VALUBusy -10pp). At 4 waves/EU the compiler
// goes spill-free (R8: VGPR 64 + AGPR persistents, clean FETCH/WRITE);
// occupancy is then LDS-bound at 5 blocks/CU thanks to the 30 KB diet.
//
// Structure exploited: H = [A | I].
//   * Parity VN (deg 1): v2c == channel LLR -> per-check constant t5;
//     CN->parity messages never computed.
//   * Info VNs counting-sorted by degree -> wave-uniform Phase A trips;
//     scan-free segment bases from 32-bin histogram arithmetic.
//   * Old c2v in registers (c2vr); fmed3 clamps (bit-identical to min/max).
//   * Atomic build order only permutes float accumulation order —
//     validated order-independent in R4-R8 (absmax 0).
//
// CN math (product form, prefix/suffix partial products, bits domain):
//   t = copysign((1-2^-av)/(1+2^-av), v2c);  q_j = t5 * prod_{i!=j} t_i
//   q = med3(q, -QC, QC);  r = log2((1+q)/(1-q))
// -------------------------------------------------------------------------
__global__ __launch_bounds__(256, 4) void link_kernel(
    const int*   __restrict__ bits,      // [B,K]
    const int*   __restrict__ a_idx,     // [M,DV]
    const float* __restrict__ points_re, // [16]
    const float* __restrict__ points_im, // [16]
    const float* __restrict__ noise_re,  // [B,NSYM]
    const float* __restrict__ noise_im,  // [B,NSYM]
    const float* __restrict__ ebno_db,   // [1]
    const int*   __restrict__ edge_vn,   // [E]
    float*       __restrict__ out)       // [2,B,K]
{
#pragma clang fp contract(off)
    const int b   = blockIdx.x;
    const int tid = threadIdx.x;

    __shared__ float s_mem[CAP_];
    __shared__ float s_marg[K_];
    __shared__ float s_pre[16];
    __shared__ float s_pim[16];
    __shared__ int   s_hist[32];
    __shared__ int   s_binStart[32];
    __shared__ int   s_binBase[32];

    // build scratch aliases the tail of s_mem (N_ + 4*K_ == CAP_ exactly)
    int* sc        = (int*)(s_mem + N_);
    int* s_deg     = sc;                 // [K] degree
    int* s_perm    = sc + K_;            // [K] slot -> v | deg<<16
    int* s_offslot = sc + 2 * K_;        // [K] v -> base | slot<<16
    int* s_cnt     = sc + 3 * K_;        // [K] edge-fill cursors

    if (tid < 16) {
        s_pre[tid] = points_re[tid];
        s_pim[tid] = points_im[tid];
    }
    if (tid < 32) s_hist[tid] = 0;

    const float eb    = ebno_db[0];
    const float no    = 1.0f / ((powf(10.0f, eb / 10.0f) * 0.5f) * 4.0f);
    const float sigma = sqrtf(no / 2.0f);

    // ---- stage info bits (0/1 floats); output0 = bits.astype(f32) ----
    for (int i = tid; i < K_; i += 256) {
        int v = bits[b * K_ + i];
        s_mem[i] = (float)v;
        out[b * K_ + i] = (float)v;
    }
    __syncthreads();

    // ---- parity: XOR of DV gathered info bits; zero build counters ----
    for (int m = tid; m < M_; m += 256) {
        float acc = 0.0f;
        #pragma unroll
        for (int d = 0; d < DV_; ++d) acc += s_mem[a_idx[m * DV_ + d]];
        s_mem[K_ + m] = (float)(((int)acc) & 1);
    }
    for (int v = tid; v < K_; v += 256) { s_deg[v] = 0; s_cnt[v] = 0; }
    __syncthreads();

    // ---- QAM + AWGN + exact APP demap (stores LLR * log2e) ----
    // ---- overlapped: VN degree count (disjoint LDS region)       ----
    for (int s = tid; s < NSYM_; s += 256) {
        int c0 = (int)s_mem[4 * s + 0];
        int c1 = (int)s_mem[4 * s + 1];
        int c2 = (int)s_mem[4 * s + 2];
        int c3 = (int)s_mem[4 * s + 3];
        int sym = c0 * 8 + c1 * 4 + c2 * 2 + c3;
        float yre = s_pre[sym] + sigma * noise_re[b * NSYM_ + s];
        float yim = s_pim[sym] + sigma * noise_im[b * NSYM_ + s];
        float lg[16];
        #pragma unroll
        for (int p = 0; p < 16; ++p) {
            float dre  = yre - s_pre[p];
            float dim_ = yim - s_pim[p];
            float d2   = dre * dre + dim_ * dim_;
            lg[p] = -d2 / no;
        }
        float llr4[4];
        #pragma unroll
        for (int j = 0; j < 4; ++j) {
            float m0 = -1e30f, m1 = -1e30f;
            #pragma unroll
            for (int p = 0; p < 16; ++p) {
                if (((p >> (3 - j)) & 1) == 0) m0 = fmaxf(m0, lg[p]);
                else                           m1 = fmaxf(m1, lg[p]);
            }
            float sum0 = 0.0f, sum1 = 0.0f;
            #pragma unroll
            for (int p = 0; p < 16; ++p) {
                if (((p >> (3 - j)) & 1) == 0) sum0 += __expf(lg[p] - m0);
                else                           sum1 += __expf(lg[p] - m1);
            }
            llr4[j] = (m0 + __logf(sum0)) - (m1 + __logf(sum1));
        }
        s_mem[4 * s + 0] = llr4[0] * LOG2E_;
        s_mem[4 * s + 1] = llr4[1] * LOG2E_;
        s_mem[4 * s + 2] = llr4[2] * LOG2E_;
        s_mem[4 * s + 3] = llr4[3] * LOG2E_;
    }
    for (int idx = tid; idx < NIE_; idx += 256) {
        int m = idx / 5, j = idx - m * 5;
        atomicAdd(&s_deg[edge_vn[m * ROW_ + j]], 1);
    }
    __syncthreads();

    // ---- degree histogram -> arithmetic segment bases (scan-free) ----
    for (int v = tid; v < K_; v += 256) atomicAdd(&s_hist[s_deg[v] & 31], 1);
    __syncthreads();
    if (tid == 0) {
        int accS = 0, accB = 0;
        for (int d = 0; d < 32; ++d) {
            int c = s_hist[d];
            s_binStart[d] = accS;
            s_binBase[d]  = accB;
            s_hist[d]     = accS;        // reuse as sort cursor
            accS += c;
            accB += c * seg_stride(d);
        }
    }
    __syncthreads();
    for (int v = tid; v < K_; v += 256) {   // counting sort by degree
        int d    = s_deg[v];
        int slot = atomicAdd(&s_hist[d & 31], 1);
        int base = s_binBase[d] + (slot - s_binStart[d]) * seg_stride(d);
        s_perm[slot]  = v | (d << 16);
        s_offslot[v]  = base | (slot << 16);
    }
    __syncthreads();

    // ---- capture iteration-invariant state in registers ----
    int      pv[5];                      // slot -> VN id
    unsigned od[5];                      // base | deg<<16
    float    lr[5];                      // channel LLR_hat of owned VN
    #pragma unroll
    for (int k = 0; k < 5; ++k) {
        int s = tid + 256 * k;
        if (s < K_) {
            int w = s_perm[s];
            int v = w & 0xFFFF;
            int d = w >> 16;
            int base = s_binBase[d] + (s - s_binStart[d]) * seg_stride(d);
            pv[k] = v;
            od[k] = (unsigned)base | ((unsigned)d << 16);
            lr[k] = s_mem[v];
        } else { pv[k] = 0; od[k] = 0; lr[k] = 0.0f; }
    }
    float    t5[5];
    unsigned vnp[5][5];                  // slot | pos<<16
    float    c2vr[5][5];                 // previous c2v (registers)
    #pragma unroll
    for (int kk = 0; kk < 5; ++kk) {
        int m = tid + 256 * kk;
        if (m < M_) {
            #pragma unroll
            for (int j = 0; j < 5; ++j) {
                int v = edge_vn[m * ROW_ + j];
                int r = atomicAdd(&s_cnt[v], 1);
                int w = s_offslot[v];
                vnp[kk][j]  = (unsigned)(w >> 16) | ((unsigned)((w & 0xFFFF) + r) << 16);
                c2vr[kk][j] = 0.0f;
            }
            float lrP = s_mem[K_ + m];
            float av  = __builtin_amdgcn_fmed3f(fabsf(lrP), AVLO_, AVHI_);
            float e   = exp2f(-av);
            float tm  = __fdividef(1.0f - e, 1.0f + e);
            t5[kk] = copysignf(tm, lrP);
        } else { t5[kk] = 0.0f; }
    }
    __syncthreads();
    // scratch fully consumed -> become the message array
    for (int i = tid; i < CAP_; i += 256) s_mem[i] = 0.0f;
    __syncthreads();

    // ---- sum-product BP, flooding (all quantities in bits domain) ----
    for (int it = 0; it < NITER_; ++it) {
        // Phase A: slot-indexed marginals; paired reads -> ds_read2_b32
        #pragma unroll
        for (int k = 0; k < 5; ++k) {
            int s = tid + 256 * k;
            if (s < K_) {
                int base = (int)(od[k] & 0xFFFFu);
                int dg   = (int)(od[k] >> 16);
                float mg = lr[k];
                int d = 0;
                for (; d + 1 < dg; d += 2) {
                    mg += s_mem[base + d];
                    mg += s_mem[base + d + 1];
                }
                if (d < dg) mg += s_mem[base + d];
                s_marg[s] = mg;
            }
        }
        __syncthreads();
        // Phase B: CN update, prefix/suffix products; old c2v in registers
        #pragma unroll
        for (int kk = 0; kk < 5; ++kk) {
            int m = tid + 256 * kk;
            if (m < M_) {
                float tj[5];
                #pragma unroll
                for (int j = 0; j < 5; ++j) {
                    unsigned w = vnp[kk][j];
                    float v2c = s_marg[w & 0xFFFFu] - c2vr[kk][j];
                    float av  = __builtin_amdgcn_fmed3f(fabsf(v2c), AVLO_, AVHI_);
                    float e   = exp2f(-av);
                    float tm  = __fdividef(1.0f - e, 1.0f + e);
                    tj[j] = copysignf(tm, v2c);
                }
                float qv[5];
                float pr = t5[kk];
                #pragma unroll
                for (int j = 0; j < 5; ++j) { qv[j] = pr; pr *= tj[j]; }
                float sf = 1.0f;
                #pragma unroll
                for (int j = 4; j >= 0; --j) { qv[j] *= sf; sf *= tj[j]; }
                #pragma unroll
                for (int j = 0; j < 5; ++j) {
                    float q = __builtin_amdgcn_fmed3f(qv[j], -QC_, QC_);
                    float r = log2f(__fdividef(1.0f + q, 1.0f - q));
                    s_mem[vnp[kk][j] >> 16] = r;
                    c2vr[kk][j] = r;
                }
            }
        }
        __syncthreads();
    }

    // ---- final marginal + hard decision on info VNs ----
    #pragma unroll
    for (int k = 0; k < 5; ++k) {
        int s = tid + 256 * k;
        if (s < K_) {
            int base = (int)(od[k] & 0xFFFFu);
            int dg   = (int)(od[k] >> 16);
            float mg = lr[k];
            int d = 0;
            for (; d + 1 < dg; d += 2) {
                mg += s_mem[base + d];
                mg += s_mem[base + d + 1];
            }
            if (d < dg) mg += s_mem[base + d];
            out[(size_t)BATCH_ * K_ + b * K_ + pv[k]] = (mg < 0.0f) ? 1.0f : 0.0f;
        }
    }
}

extern "C" void kernel_launch(void* const* d_in, const int* in_sizes, int n_in,
                              void* d_out, int out_size, void* d_ws, size_t ws_size,
                              hipStream_t stream) {
    const int*   bits    = (const int*)  d_in[0];
    const int*   a_idx   = (const int*)  d_in[1];
    // d_in[2] = edge_cn (implicit: contiguous groups of 6) — unused
    const int*   edge_vn = (const int*)  d_in[3];
    const float* pre     = (const float*)d_in[4];
    const float* pim     = (const float*)d_in[5];
    const float* nre     = (const float*)d_in[6];
    const float* nim     = (const float*)d_in[7];
    const float* ebno    = (const float*)d_in[8];

    link_kernel<<<BATCH_, 256, 0, stream>>>(bits, a_idx, pre, pim, nre, nim,
                                            ebno, edge_vn, (float*)d_out);
}

// Round 12
// 257.380 us; speedup vs baseline: 1.0630x; 1.0049x over previous
//
#include <hip/hip_runtime.h>

// Problem constants (match reference)
#define K_     1056
#define N_     2112
#define M_     1056   // N - K
#define E_     6336   // M * 6
#define NIE_   5280   // M * 5 info-side edges (the only BP state; compact)
#define ALL_   6336   // NIE_ + K_ : c2v + marg unified array (= N_ + 4K build scratch)
#define DV_    5
#define ROW_   6      // edge 6m+5 is the parity VN K+m
#define NSYM_  528
#define NITER_ 20
#define BATCH_ 1024

#define LOG2E_ 1.4426950408889634f
#define AVLO_  (1e-6f * LOG2E_)          // |v2c| floor, bits units
#define AVHI_  (20.0f * LOG2E_)          // |v2c| cap,  bits units
#define QC_    0.99999988f               // tanh-domain cap (unchanged)

// -------------------------------------------------------------------------
// Single kernel, one block per codeword. Base-2 LLR domain after demap
// (LLR_hat = LLR * log2e): v_exp_f32/v_log_f32 are natively 2^x/log2(x).
// Hard decisions are invariant under the positive scaling.
//
// LDS (~25.9 KB -> 6 blocks/CU, 24 waves — the R11 change):
//   s_all[6336]: one unified array.
//     build:  [0..N) staging (bits -> LLR_hat), [N..6336) int scratch
//             (deg|perm|offslot|cnt = 4*K, EXACT fit: N+4K == 6336)
//     BP:     [0..NIE) c2v messages, COMPACT VN-major segments (no pad),
//             [NIE..6336) slot-indexed marginals (K floats)
//   Compact segments re-admit even-degree bank conflicts in Phase A
//   (deg 4 -> 8-way etc.), but Phase A is ~6% of hot-loop issue slots;
//   the occupancy gain (5 -> 6 blocks/CU) dominates.
//
// NOTE __launch_bounds__(256, 4): (256,5) made the allocator collapse to
// 48 VGPRs and spill ~34 MB/dispatch (R9). At 4 waves/EU it is spill-free
// (VGPR ~60); runtime occupancy is then LDS-bound at 6 blocks/CU.
//
// Structure exploited: H = [A | I].
//   * Parity VN (deg 1): v2c == channel LLR -> per-check constant t5;
//     CN->parity messages never computed.
//   * Info VNs counting-sorted by degree -> wave-uniform Phase A trips;
//     scan-free segment bases from 32-bin histogram arithmetic.
//   * Old c2v in registers (c2vr); fmed3 clamps (bit-identical to min/max).
//   * Atomic build order only permutes float accumulation order —
//     validated order-independent in R4-R10 (absmax 0).
//
// CN math (product form, prefix/suffix partial products, bits domain):
//   t = copysign((1-2^-av)/(1+2^-av), v2c);  q_j = t5 * prod_{i!=j} t_i
//   q = med3(q, -QC, QC);  r = log2((1+q)/(1-q))
// -------------------------------------------------------------------------
__global__ __launch_bounds__(256, 4) void link_kernel(
    const int*   __restrict__ bits,      // [B,K]
    const int*   __restrict__ a_idx,     // [M,DV]
    const float* __restrict__ points_re, // [16]
    const float* __restrict__ points_im, // [16]
    const float* __restrict__ noise_re,  // [B,NSYM]
    const float* __restrict__ noise_im,  // [B,NSYM]
    const float* __restrict__ ebno_db,   // [1]
    const int*   __restrict__ edge_vn,   // [E]
    float*       __restrict__ out)       // [2,B,K]
{
#pragma clang fp contract(off)
    const int b   = blockIdx.x;
    const int tid = threadIdx.x;

    __shared__ float s_all[ALL_];
    __shared__ float s_pre[16];
    __shared__ float s_pim[16];
    __shared__ int   s_hist[32];
    __shared__ int   s_binStart[32];
    __shared__ int   s_binBase[32];

    float* s_mem  = s_all;               // staging, later c2v [0..NIE)
    float* s_marg = s_all + NIE_;        // BP marginals [NIE..6336)

    // build scratch aliases [N..6336): N + 4K == ALL_ exactly
    int* sc        = (int*)(s_all + N_);
    int* s_deg     = sc;                 // [K] degree
    int* s_perm    = sc + K_;            // [K] slot -> v | deg<<16
    int* s_offslot = sc + 2 * K_;        // [K] v -> base | slot<<16
    int* s_cnt     = sc + 3 * K_;        // [K] edge-fill cursors (== s_marg region; dead after build)

    if (tid < 16) {
        s_pre[tid] = points_re[tid];
        s_pim[tid] = points_im[tid];
    }
    if (tid < 32) s_hist[tid] = 0;

    const float eb    = ebno_db[0];
    const float no    = 1.0f / ((powf(10.0f, eb / 10.0f) * 0.5f) * 4.0f);
    const float sigma = sqrtf(no / 2.0f);

    // ---- stage info bits (0/1 floats); output0 = bits.astype(f32) ----
    for (int i = tid; i < K_; i += 256) {
        int v = bits[b * K_ + i];
        s_mem[i] = (float)v;
        out[b * K_ + i] = (float)v;
    }
    __syncthreads();

    // ---- parity: XOR of DV gathered info bits; zero build counters ----
    for (int m = tid; m < M_; m += 256) {
        float acc = 0.0f;
        #pragma unroll
        for (int d = 0; d < DV_; ++d) acc += s_mem[a_idx[m * DV_ + d]];
        s_mem[K_ + m] = (float)(((int)acc) & 1);
    }
    for (int v = tid; v < K_; v += 256) { s_deg[v] = 0; s_cnt[v] = 0; }
    __syncthreads();

    // ---- QAM + AWGN + exact APP demap (stores LLR * log2e) ----
    // ---- overlapped: VN degree count (disjoint LDS region)       ----
    for (int s = tid; s < NSYM_; s += 256) {
        int c0 = (int)s_mem[4 * s + 0];
        int c1 = (int)s_mem[4 * s + 1];
        int c2 = (int)s_mem[4 * s + 2];
        int c3 = (int)s_mem[4 * s + 3];
        int sym = c0 * 8 + c1 * 4 + c2 * 2 + c3;
        float yre = s_pre[sym] + sigma * noise_re[b * NSYM_ + s];
        float yim = s_pim[sym] + sigma * noise_im[b * NSYM_ + s];
        float lg[16];
        #pragma unroll
        for (int p = 0; p < 16; ++p) {
            float dre  = yre - s_pre[p];
            float dim_ = yim - s_pim[p];
            float d2   = dre * dre + dim_ * dim_;
            lg[p] = -d2 / no;
        }
        float llr4[4];
        #pragma unroll
        for (int j = 0; j < 4; ++j) {
            float m0 = -1e30f, m1 = -1e30f;
            #pragma unroll
            for (int p = 0; p < 16; ++p) {
                if (((p >> (3 - j)) & 1) == 0) m0 = fmaxf(m0, lg[p]);
                else                           m1 = fmaxf(m1, lg[p]);
            }
            float sum0 = 0.0f, sum1 = 0.0f;
            #pragma unroll
            for (int p = 0; p < 16; ++p) {
                if (((p >> (3 - j)) & 1) == 0) sum0 += __expf(lg[p] - m0);
                else                           sum1 += __expf(lg[p] - m1);
            }
            llr4[j] = (m0 + __logf(sum0)) - (m1 + __logf(sum1));
        }
        s_mem[4 * s + 0] = llr4[0] * LOG2E_;
        s_mem[4 * s + 1] = llr4[1] * LOG2E_;
        s_mem[4 * s + 2] = llr4[2] * LOG2E_;
        s_mem[4 * s + 3] = llr4[3] * LOG2E_;
    }
    for (int idx = tid; idx < NIE_; idx += 256) {
        int m = idx / 5, j = idx - m * 5;
        atomicAdd(&s_deg[edge_vn[m * ROW_ + j]], 1);
    }
    __syncthreads();

    // ---- degree histogram -> arithmetic segment bases (scan-free) ----
    for (int v = tid; v < K_; v += 256) atomicAdd(&s_hist[s_deg[v] & 31], 1);
    __syncthreads();
    if (tid == 0) {
        int accS = 0, accB = 0;
        for (int d = 0; d < 32; ++d) {
            int c = s_hist[d];
            s_binStart[d] = accS;
            s_binBase[d]  = accB;
            s_hist[d]     = accS;        // reuse as sort cursor
            accS += c;
            accB += c * d;               // compact: stride == degree
        }
    }
    __syncthreads();
    for (int v = tid; v < K_; v += 256) {   // counting sort by degree
        int d    = s_deg[v];
        int slot = atomicAdd(&s_hist[d & 31], 1);
        int base = s_binBase[d] + (slot - s_binStart[d]) * d;
        s_perm[slot]  = v | (d << 16);
        s_offslot[v]  = base | (slot << 16);
    }
    __syncthreads();

    // ---- capture iteration-invariant state in registers ----
    int      pv[5];                      // slot -> VN id
    unsigned od[5];                      // base | deg<<16
    float    lr[5];                      // channel LLR_hat of owned VN
    #pragma unroll
    for (int k = 0; k < 5; ++k) {
        int s = tid + 256 * k;
        if (s < K_) {
            int w = s_perm[s];
            int v = w & 0xFFFF;
            int d = w >> 16;
            int base = s_binBase[d] + (s - s_binStart[d]) * d;
            pv[k] = v;
            od[k] = (unsigned)base | ((unsigned)d << 16);
            lr[k] = s_mem[v];
        } else { pv[k] = 0; od[k] = 0; lr[k] = 0.0f; }
    }
    float    t5[5];
    unsigned vnp[5][5];                  // slot | pos<<16
    float    c2vr[5][5];                 // previous c2v (registers)
    #pragma unroll
    for (int kk = 0; kk < 5; ++kk) {
        int m = tid + 256 * kk;
        if (m < M_) {
            #pragma unroll
            for (int j = 0; j < 5; ++j) {
                int v = edge_vn[m * ROW_ + j];
                int r = atomicAdd(&s_cnt[v], 1);
                int w = s_offslot[v];
                vnp[kk][j]  = (unsigned)(w >> 16) | ((unsigned)((w & 0xFFFF) + r) << 16);
                c2vr[kk][j] = 0.0f;
            }
            float lrP = s_mem[K_ + m];
            float av  = __builtin_amdgcn_fmed3f(fabsf(lrP), AVLO_, AVHI_);
            float e   = exp2f(-av);
            float tm  = __fdividef(1.0f - e, 1.0f + e);
            t5[kk] = copysignf(tm, lrP);
        } else { t5[kk] = 0.0f; }
    }
    __syncthreads();
    // scratch fully consumed -> become the message array
    for (int i = tid; i < NIE_; i += 256) s_mem[i] = 0.0f;
    __syncthreads();

    // ---- sum-product BP, flooding (all quantities in bits domain) ----
    for (int it = 0; it < NITER_; ++it) {
        // Phase A: slot-indexed marginals; paired reads -> ds_read2_b32
        #pragma unroll
        for (int k = 0; k < 5; ++k) {
            int s = tid + 256 * k;
            if (s < K_) {
                int base = (int)(od[k] & 0xFFFFu);
                int dg   = (int)(od[k] >> 16);
                float mg = lr[k];
                int d = 0;
                for (; d + 1 < dg; d += 2) {
                    mg += s_mem[base + d];
                    mg += s_mem[base + d + 1];
                }
                if (d < dg) mg += s_mem[base + d];
                s_marg[s] = mg;
            }
        }
        __syncthreads();
        // Phase B: CN update, prefix/suffix products; old c2v in registers
        #pragma unroll
        for (int kk = 0; kk < 5; ++kk) {
            int m = tid + 256 * kk;
            if (m < M_) {
                float tj[5];
                #pragma unroll
                for (int j = 0; j < 5; ++j) {
                    unsigned w = vnp[kk][j];
                    float v2c = s_marg[w & 0xFFFFu] - c2vr[kk][j];
                    float av  = __builtin_amdgcn_fmed3f(fabsf(v2c), AVLO_, AVHI_);
                    float e   = exp2f(-av);
                    float tm  = __fdividef(1.0f - e, 1.0f + e);
                    tj[j] = copysignf(tm, v2c);
                }
                float qv[5];
                float pr = t5[kk];
                #pragma unroll
                for (int j = 0; j < 5; ++j) { qv[j] = pr; pr *= tj[j]; }
                float sf = 1.0f;
                #pragma unroll
                for (int j = 4; j >= 0; --j) { qv[j] *= sf; sf *= tj[j]; }
                #pragma unroll
                for (int j = 0; j < 5; ++j) {
                    float q = __builtin_amdgcn_fmed3f(qv[j], -QC_, QC_);
                    float r = log2f(__fdividef(1.0f + q, 1.0f - q));
                    s_mem[vnp[kk][j] >> 16] = r;
                    c2vr[kk][j] = r;
                }
            }
        }
        __syncthreads();
    }

    // ---- final marginal + hard decision on info VNs ----
    #pragma unroll
    for (int k = 0; k < 5; ++k) {
        int s = tid + 256 * k;
        if (s < K_) {
            int base = (int)(od[k] & 0xFFFFu);
            int dg   = (int)(od[k] >> 16);
            float mg = lr[k];
            int d = 0;
            for (; d + 1 < dg; d += 2) {
                mg += s_mem[base + d];
                mg += s_mem[base + d + 1];
            }
            if (d < dg) mg += s_mem[base + d];
            out[(size_t)BATCH_ * K_ + b * K_ + pv[k]] = (mg < 0.0f) ? 1.0f : 0.0f;
        }
    }
}

extern "C" void kernel_launch(void* const* d_in, const int* in_sizes, int n_in,
                              void* d_out, int out_size, void* d_ws, size_t ws_size,
                              hipStream_t stream) {
    const int*   bits    = (const int*)  d_in[0];
    const int*   a_idx   = (const int*)  d_in[1];
    // d_in[2] = edge_cn (implicit: contiguous groups of 6) — unused
    const int*   edge_vn = (const int*)  d_in[3];
    const float* pre     = (const float*)d_in[4];
    const float* pim     = (const float*)d_in[5];
    const float* nre     = (const float*)d_in[6];
    const float* nim     = (const float*)d_in[7];
    const float* ebno    = (const float*)d_in[8];

    link_kernel<<<BATCH_, 256, 0, stream>>>(bits, a_idx, pre, pim, nre, nim,
                                            ebno, edge_vn, (float*)d_out);
}

// Round 13
// 247.550 us; speedup vs baseline: 1.1052x; 1.0397x over previous
//
#include <hip/hip_runtime.h>

// Problem constants (match reference)
#define K_     1056
#define N_     2112
#define M_     1056   // N - K
#define E_     6336   // M * 6
#define NIE_   5280   // M * 5 info-side edges (the only BP state; compact)
#define ALL_   6336   // NIE_ + K_ : c2v + marg unified array (= N_ + 4K build scratch)
#define DV_    5
#define ROW_   6      // edge 6m+5 is the parity VN K+m
#define NSYM_  528
#define NITER_ 20
#define BATCH_ 1024
#define BS_    512    // threads/block: 8 waves -> 4 blocks/CU fills all 32 wave slots

#define LOG2E_ 1.4426950408889634f
#define AVLO_  (1e-6f * LOG2E_)          // |v2c| floor, bits units
#define AVHI_  (20.0f * LOG2E_)          // |v2c| cap,  bits units
#define QC_    0.99999988f               // tanh-domain cap (unchanged)

// -------------------------------------------------------------------------
// Single kernel, one block per codeword, 512 threads (R12 change).
// Rationale: grid is fixed at 1024 blocks = 4 blocks/CU, so per-CU wave
// residency is 4 * (block waves). At 256 threads that capped us at 16
// waves/CU (50%); 512-thread blocks give 32 waves/CU (100%) while halving
// per-thread persistent state (~45 regs -> fits the 64-VGPR/8-wave budget).
//
// Base-2 LLR domain after demap (LLR_hat = LLR * log2e): v_exp_f32 /
// v_log_f32 are natively 2^x / log2(x). Hard decisions scale-invariant.
//
// LDS (~25.9 KB): s_all[6336] unified —
//   build: [0..N) staging (bits -> LLR_hat), [N..6336) int scratch
//          (deg|perm|offslot|cnt = 4*K, EXACT fit: N+4K == 6336)
//   BP:    [0..NIE) c2v compact VN-major segments, [NIE..6336) marginals
//
// Structure exploited: H = [A | I].
//   * Parity VN (deg 1): v2c == channel LLR -> per-check constant t5.
//   * Info VNs counting-sorted by degree -> wave-uniform Phase A trips;
//     scan-free segment bases from 32-bin histogram arithmetic.
//   * Old c2v in registers (c2vr); fmed3 clamps.
//   * Atomic build order only permutes float accumulation order —
//     validated order-independent in R4-R11 (absmax 0).
//
// CN math (product form, prefix/suffix partial products, bits domain):
//   t = copysign((1-2^-av)/(1+2^-av), v2c);  q_j = t5 * prod_{i!=j} t_i
//   q = med3(q, -QC, QC);  r = log2((1+q)/(1-q))
// -------------------------------------------------------------------------
__global__ __launch_bounds__(BS_, 8) void link_kernel(
    const int*   __restrict__ bits,      // [B,K]
    const int*   __restrict__ a_idx,     // [M,DV]
    const float* __restrict__ points_re, // [16]
    const float* __restrict__ points_im, // [16]
    const float* __restrict__ noise_re,  // [B,NSYM]
    const float* __restrict__ noise_im,  // [B,NSYM]
    const float* __restrict__ ebno_db,   // [1]
    const int*   __restrict__ edge_vn,   // [E]
    float*       __restrict__ out)       // [2,B,K]
{
#pragma clang fp contract(off)
    const int b   = blockIdx.x;
    const int tid = threadIdx.x;

    __shared__ float s_all[ALL_];
    __shared__ float s_pre[16];
    __shared__ float s_pim[16];
    __shared__ int   s_hist[32];
    __shared__ int   s_binStart[32];
    __shared__ int   s_binBase[32];

    float* s_mem  = s_all;               // staging, later c2v [0..NIE)
    float* s_marg = s_all + NIE_;        // BP marginals [NIE..6336)

    // build scratch aliases [N..6336): N + 4K == ALL_ exactly
    int* sc        = (int*)(s_all + N_);
    int* s_deg     = sc;                 // [K] degree
    int* s_perm    = sc + K_;            // [K] slot -> v | deg<<16
    int* s_offslot = sc + 2 * K_;        // [K] v -> base | slot<<16
    int* s_cnt     = sc + 3 * K_;        // [K] edge-fill cursors

    if (tid < 16) {
        s_pre[tid] = points_re[tid];
        s_pim[tid] = points_im[tid];
    }
    if (tid < 32) s_hist[tid] = 0;

    const float eb    = ebno_db[0];
    const float no    = 1.0f / ((powf(10.0f, eb / 10.0f) * 0.5f) * 4.0f);
    const float sigma = sqrtf(no / 2.0f);

    // ---- stage info bits (0/1 floats); output0 = bits.astype(f32) ----
    for (int i = tid; i < K_; i += BS_) {
        int v = bits[b * K_ + i];
        s_mem[i] = (float)v;
        out[b * K_ + i] = (float)v;
    }
    __syncthreads();

    // ---- parity: XOR of DV gathered info bits; zero build counters ----
    for (int m = tid; m < M_; m += BS_) {
        float acc = 0.0f;
        #pragma unroll
        for (int d = 0; d < DV_; ++d) acc += s_mem[a_idx[m * DV_ + d]];
        s_mem[K_ + m] = (float)(((int)acc) & 1);
    }
    for (int v = tid; v < K_; v += BS_) { s_deg[v] = 0; s_cnt[v] = 0; }
    __syncthreads();

    // ---- QAM + AWGN + exact APP demap (stores LLR * log2e) ----
    // ---- overlapped: VN degree count (disjoint LDS region)       ----
    for (int s = tid; s < NSYM_; s += BS_) {
        int c0 = (int)s_mem[4 * s + 0];
        int c1 = (int)s_mem[4 * s + 1];
        int c2 = (int)s_mem[4 * s + 2];
        int c3 = (int)s_mem[4 * s + 3];
        int sym = c0 * 8 + c1 * 4 + c2 * 2 + c3;
        float yre = s_pre[sym] + sigma * noise_re[b * NSYM_ + s];
        float yim = s_pim[sym] + sigma * noise_im[b * NSYM_ + s];
        float lg[16];
        #pragma unroll
        for (int p = 0; p < 16; ++p) {
            float dre  = yre - s_pre[p];
            float dim_ = yim - s_pim[p];
            float d2   = dre * dre + dim_ * dim_;
            lg[p] = -d2 / no;
        }
        float llr4[4];
        #pragma unroll
        for (int j = 0; j < 4; ++j) {
            float m0 = -1e30f, m1 = -1e30f;
            #pragma unroll
            for (int p = 0; p < 16; ++p) {
                if (((p >> (3 - j)) & 1) == 0) m0 = fmaxf(m0, lg[p]);
                else                           m1 = fmaxf(m1, lg[p]);
            }
            float sum0 = 0.0f, sum1 = 0.0f;
            #pragma unroll
            for (int p = 0; p < 16; ++p) {
                if (((p >> (3 - j)) & 1) == 0) sum0 += __expf(lg[p] - m0);
                else                           sum1 += __expf(lg[p] - m1);
            }
            llr4[j] = (m0 + __logf(sum0)) - (m1 + __logf(sum1));
        }
        s_mem[4 * s + 0] = llr4[0] * LOG2E_;
        s_mem[4 * s + 1] = llr4[1] * LOG2E_;
        s_mem[4 * s + 2] = llr4[2] * LOG2E_;
        s_mem[4 * s + 3] = llr4[3] * LOG2E_;
    }
    for (int idx = tid; idx < NIE_; idx += BS_) {
        int m = idx / 5, j = idx - m * 5;
        atomicAdd(&s_deg[edge_vn[m * ROW_ + j]], 1);
    }
    __syncthreads();

    // ---- degree histogram -> arithmetic segment bases (scan-free) ----
    for (int v = tid; v < K_; v += BS_) atomicAdd(&s_hist[s_deg[v] & 31], 1);
    __syncthreads();
    if (tid == 0) {
        int accS = 0, accB = 0;
        for (int d = 0; d < 32; ++d) {
            int c = s_hist[d];
            s_binStart[d] = accS;
            s_binBase[d]  = accB;
            s_hist[d]     = accS;        // reuse as sort cursor
            accS += c;
            accB += c * d;               // compact: stride == degree
        }
    }
    __syncthreads();
    for (int v = tid; v < K_; v += BS_) {   // counting sort by degree
        int d    = s_deg[v];
        int slot = atomicAdd(&s_hist[d & 31], 1);
        int base = s_binBase[d] + (slot - s_binStart[d]) * d;
        s_perm[slot]  = v | (d << 16);
        s_offslot[v]  = base | (slot << 16);
    }
    __syncthreads();

    // ---- capture iteration-invariant state in registers ----
    int      pv[3];                      // slot -> VN id
    unsigned od[3];                      // base | deg<<16
    float    lr[3];                      // channel LLR_hat of owned VN
    #pragma unroll
    for (int k = 0; k < 3; ++k) {
        int s = tid + BS_ * k;
        if (s < K_) {
            int w = s_perm[s];
            int v = w & 0xFFFF;
            int d = w >> 16;
            int base = s_binBase[d] + (s - s_binStart[d]) * d;
            pv[k] = v;
            od[k] = (unsigned)base | ((unsigned)d << 16);
            lr[k] = s_mem[v];
        } else { pv[k] = 0; od[k] = 0; lr[k] = 0.0f; }
    }
    float    t5[3];
    unsigned vnp[3][5];                  // slot | pos<<16
    float    c2vr[3][5];                 // previous c2v (registers)
    #pragma unroll
    for (int kk = 0; kk < 3; ++kk) {
        int m = tid + BS_ * kk;
        if (m < M_) {
            #pragma unroll
            for (int j = 0; j < 5; ++j) {
                int v = edge_vn[m * ROW_ + j];
                int r = atomicAdd(&s_cnt[v], 1);
                int w = s_offslot[v];
                vnp[kk][j]  = (unsigned)(w >> 16) | ((unsigned)((w & 0xFFFF) + r) << 16);
                c2vr[kk][j] = 0.0f;
            }
            float lrP = s_mem[K_ + m];
            float av  = __builtin_amdgcn_fmed3f(fabsf(lrP), AVLO_, AVHI_);
            float e   = exp2f(-av);
            float tm  = __fdividef(1.0f - e, 1.0f + e);
            t5[kk] = copysignf(tm, lrP);
        } else { t5[kk] = 0.0f; }
    }
    __syncthreads();
    // scratch fully consumed -> become the message array
    for (int i = tid; i < NIE_; i += BS_) s_mem[i] = 0.0f;
    __syncthreads();

    // ---- sum-product BP, flooding (all quantities in bits domain) ----
    for (int it = 0; it < NITER_; ++it) {
        // Phase A: slot-indexed marginals; paired reads -> ds_read2_b32
        #pragma unroll
        for (int k = 0; k < 3; ++k) {
            int s = tid + BS_ * k;
            if (s < K_) {
                int base = (int)(od[k] & 0xFFFFu);
                int dg   = (int)(od[k] >> 16);
                float mg = lr[k];
                int d = 0;
                for (; d + 1 < dg; d += 2) {
                    mg += s_mem[base + d];
                    mg += s_mem[base + d + 1];
                }
                if (d < dg) mg += s_mem[base + d];
                s_marg[s] = mg;
            }
        }
        __syncthreads();
        // Phase B: CN update, prefix/suffix products; old c2v in registers
        #pragma unroll
        for (int kk = 0; kk < 3; ++kk) {
            int m = tid + BS_ * kk;
            if (m < M_) {
                float tj[5];
                #pragma unroll
                for (int j = 0; j < 5; ++j) {
                    unsigned w = vnp[kk][j];
                    float v2c = s_marg[w & 0xFFFFu] - c2vr[kk][j];
                    float av  = __builtin_amdgcn_fmed3f(fabsf(v2c), AVLO_, AVHI_);
                    float e   = exp2f(-av);
                    float tm  = __fdividef(1.0f - e, 1.0f + e);
                    tj[j] = copysignf(tm, v2c);
                }
                float qv[5];
                float pr = t5[kk];
                #pragma unroll
                for (int j = 0; j < 5; ++j) { qv[j] = pr; pr *= tj[j]; }
                float sf = 1.0f;
                #pragma unroll
                for (int j = 4; j >= 0; --j) { qv[j] *= sf; sf *= tj[j]; }
                #pragma unroll
                for (int j = 0; j < 5; ++j) {
                    float q = __builtin_amdgcn_fmed3f(qv[j], -QC_, QC_);
                    float r = log2f(__fdividef(1.0f + q, 1.0f - q));
                    s_mem[vnp[kk][j] >> 16] = r;
                    c2vr[kk][j] = r;
                }
            }
        }
        __syncthreads();
    }

    // ---- final marginal + hard decision on info VNs ----
    #pragma unroll
    for (int k = 0; k < 3; ++k) {
        int s = tid + BS_ * k;
        if (s < K_) {
            int base = (int)(od[k] & 0xFFFFu);
            int dg   = (int)(od[k] >> 16);
            float mg = lr[k];
            int d = 0;
            for (; d + 1 < dg; d += 2) {
                mg += s_mem[base + d];
                mg += s_mem[base + d + 1];
            }
            if (d < dg) mg += s_mem[base + d];
            out[(size_t)BATCH_ * K_ + b * K_ + pv[k]] = (mg < 0.0f) ? 1.0f : 0.0f;
        }
    }
}

extern "C" void kernel_launch(void* const* d_in, const int* in_sizes, int n_in,
                              void* d_out, int out_size, void* d_ws, size_t ws_size,
                              hipStream_t stream) {
    const int*   bits    = (const int*)  d_in[0];
    const int*   a_idx   = (const int*)  d_in[1];
    // d_in[2] = edge_cn (implicit: contiguous groups of 6) — unused
    const int*   edge_vn = (const int*)  d_in[3];
    const float* pre     = (const float*)d_in[4];
    const float* pim     = (const float*)d_in[5];
    const float* nre     = (const float*)d_in[6];
    const float* nim     = (const float*)d_in[7];
    const float* ebno    = (const float*)d_in[8];

    link_kernel<<<BATCH_, BS_, 0, stream>>>(bits, a_idx, pre, pim, nre, nim,
                                            ebno, edge_vn, (float*)d_out);
}

// Round 14
// 244.550 us; speedup vs baseline: 1.1188x; 1.0123x over previous
//
#include <hip/hip_runtime.h>

// Problem constants (match reference)
#define K_     1056
#define N_     2112
#define M_     1056   // N - K
#define E_     6336   // M * 6
#define NIE_   5280   // M * 5 info-side edges (the only BP state; compact)
#define ALL_   6336   // NIE_ + K_ : c2v + marg unified array (= N_ + 4K build scratch)
#define DV_    5
#define ROW_   6      // edge 6m+5 is the parity VN K+m
#define NSYM_  528
#define NITER_ 20
#define BATCH_ 1024
#define BS_    512    // threads/block: 8 waves -> 4 blocks/CU fills all 32 wave slots

#define LOG2E_ 1.4426950408889634f
#define AVLO_  (1e-6f * LOG2E_)          // |v2c| floor, bits units
#define AVHI_  (20.0f * LOG2E_)          // |v2c| cap,  bits units
#define QC_    0.99999988f               // tanh-domain cap (unchanged)

// -------------------------------------------------------------------------
// Single kernel, one block per codeword, 512 threads / 8 waves.
// R13 change: NO c2vr register shadow — Phase B re-reads the old c2v from
// LDS (single writer == single reader per position, read-before-write
// within the same thread; R6-proven). This drops live VGPRs from ~75 to
// ~55 so the allocator can genuinely fit the 64-VGPR / 8-waves-per-SIMD
// budget instead of collapsing to 32 + scratch spills (R12: FETCH 22.5 MB,
// WRITE 63.7 MB of spill traffic).
//
// Base-2 LLR domain after demap (LLR_hat = LLR * log2e): v_exp_f32 /
// v_log_f32 are natively 2^x / log2(x). Hard decisions scale-invariant.
//
// LDS (~25.9 KB): s_all[6336] unified —
//   build: [0..N) staging (bits -> LLR_hat), [N..6336) int scratch
//          (deg|perm|offslot|cnt = 4*K, EXACT fit: N+4K == 6336)
//   BP:    [0..NIE) c2v compact VN-major segments, [NIE..6336) marginals
//
// Structure exploited: H = [A | I].
//   * Parity VN (deg 1): v2c == channel LLR -> per-check constant t5.
//   * Info VNs counting-sorted by degree -> wave-uniform Phase A trips;
//     scan-free segment bases from 32-bin histogram arithmetic.
//   * fmed3 clamps (bit-identical to min/max for non-NaN).
//   * Atomic build order only permutes float accumulation order —
//     validated order-independent in R4-R12 (absmax 0).
//
// CN math (product form, prefix/suffix partial products, bits domain):
//   t = copysign((1-2^-av)/(1+2^-av), v2c);  q_j = t5 * prod_{i!=j} t_i
//   q = med3(q, -QC, QC);  r = log2((1+q)/(1-q))
// -------------------------------------------------------------------------
__global__ __launch_bounds__(BS_, 8) void link_kernel(
    const int*   __restrict__ bits,      // [B,K]
    const int*   __restrict__ a_idx,     // [M,DV]
    const float* __restrict__ points_re, // [16]
    const float* __restrict__ points_im, // [16]
    const float* __restrict__ noise_re,  // [B,NSYM]
    const float* __restrict__ noise_im,  // [B,NSYM]
    const float* __restrict__ ebno_db,   // [1]
    const int*   __restrict__ edge_vn,   // [E]
    float*       __restrict__ out)       // [2,B,K]
{
#pragma clang fp contract(off)
    const int b   = blockIdx.x;
    const int tid = threadIdx.x;

    __shared__ float s_all[ALL_];
    __shared__ float s_pre[16];
    __shared__ float s_pim[16];
    __shared__ int   s_hist[32];
    __shared__ int   s_binStart[32];
    __shared__ int   s_binBase[32];

    float* s_mem  = s_all;               // staging, later c2v [0..NIE)
    float* s_marg = s_all + NIE_;        // BP marginals [NIE..6336)

    // build scratch aliases [N..6336): N + 4K == ALL_ exactly
    int* sc        = (int*)(s_all + N_);
    int* s_deg     = sc;                 // [K] degree
    int* s_perm    = sc + K_;            // [K] slot -> v | deg<<16
    int* s_offslot = sc + 2 * K_;        // [K] v -> base | slot<<16
    int* s_cnt     = sc + 3 * K_;        // [K] edge-fill cursors

    if (tid < 16) {
        s_pre[tid] = points_re[tid];
        s_pim[tid] = points_im[tid];
    }
    if (tid < 32) s_hist[tid] = 0;

    const float eb    = ebno_db[0];
    const float no    = 1.0f / ((powf(10.0f, eb / 10.0f) * 0.5f) * 4.0f);
    const float sigma = sqrtf(no / 2.0f);

    // ---- stage info bits (0/1 floats); output0 = bits.astype(f32) ----
    for (int i = tid; i < K_; i += BS_) {
        int v = bits[b * K_ + i];
        s_mem[i] = (float)v;
        out[b * K_ + i] = (float)v;
    }
    __syncthreads();

    // ---- parity: XOR of DV gathered info bits; zero build counters ----
    for (int m = tid; m < M_; m += BS_) {
        float acc = 0.0f;
        #pragma unroll
        for (int d = 0; d < DV_; ++d) acc += s_mem[a_idx[m * DV_ + d]];
        s_mem[K_ + m] = (float)(((int)acc) & 1);
    }
    for (int v = tid; v < K_; v += BS_) { s_deg[v] = 0; s_cnt[v] = 0; }
    __syncthreads();

    // ---- QAM + AWGN + exact APP demap (stores LLR * log2e) ----
    // ---- overlapped: VN degree count (disjoint LDS region)       ----
    for (int s = tid; s < NSYM_; s += BS_) {
        int c0 = (int)s_mem[4 * s + 0];
        int c1 = (int)s_mem[4 * s + 1];
        int c2 = (int)s_mem[4 * s + 2];
        int c3 = (int)s_mem[4 * s + 3];
        int sym = c0 * 8 + c1 * 4 + c2 * 2 + c3;
        float yre = s_pre[sym] + sigma * noise_re[b * NSYM_ + s];
        float yim = s_pim[sym] + sigma * noise_im[b * NSYM_ + s];
        float lg[16];
        #pragma unroll
        for (int p = 0; p < 16; ++p) {
            float dre  = yre - s_pre[p];
            float dim_ = yim - s_pim[p];
            float d2   = dre * dre + dim_ * dim_;
            lg[p] = -d2 / no;
        }
        float llr4[4];
        #pragma unroll
        for (int j = 0; j < 4; ++j) {
            float m0 = -1e30f, m1 = -1e30f;
            #pragma unroll
            for (int p = 0; p < 16; ++p) {
                if (((p >> (3 - j)) & 1) == 0) m0 = fmaxf(m0, lg[p]);
                else                           m1 = fmaxf(m1, lg[p]);
            }
            float sum0 = 0.0f, sum1 = 0.0f;
            #pragma unroll
            for (int p = 0; p < 16; ++p) {
                if (((p >> (3 - j)) & 1) == 0) sum0 += __expf(lg[p] - m0);
                else                           sum1 += __expf(lg[p] - m1);
            }
            llr4[j] = (m0 + __logf(sum0)) - (m1 + __logf(sum1));
        }
        s_mem[4 * s + 0] = llr4[0] * LOG2E_;
        s_mem[4 * s + 1] = llr4[1] * LOG2E_;
        s_mem[4 * s + 2] = llr4[2] * LOG2E_;
        s_mem[4 * s + 3] = llr4[3] * LOG2E_;
    }
    for (int idx = tid; idx < NIE_; idx += BS_) {
        int m = idx / 5, j = idx - m * 5;
        atomicAdd(&s_deg[edge_vn[m * ROW_ + j]], 1);
    }
    __syncthreads();

    // ---- degree histogram -> arithmetic segment bases (scan-free) ----
    for (int v = tid; v < K_; v += BS_) atomicAdd(&s_hist[s_deg[v] & 31], 1);
    __syncthreads();
    if (tid == 0) {
        int accS = 0, accB = 0;
        for (int d = 0; d < 32; ++d) {
            int c = s_hist[d];
            s_binStart[d] = accS;
            s_binBase[d]  = accB;
            s_hist[d]     = accS;        // reuse as sort cursor
            accS += c;
            accB += c * d;               // compact: stride == degree
        }
    }
    __syncthreads();
    for (int v = tid; v < K_; v += BS_) {   // counting sort by degree
        int d    = s_deg[v];
        int slot = atomicAdd(&s_hist[d & 31], 1);
        int base = s_binBase[d] + (slot - s_binStart[d]) * d;
        s_perm[slot]  = v | (d << 16);
        s_offslot[v]  = base | (slot << 16);
    }
    __syncthreads();

    // ---- capture iteration-invariant state in registers ----
    int      pv[3];                      // slot -> VN id
    unsigned od[3];                      // base | deg<<16
    float    lr[3];                      // channel LLR_hat of owned VN
    #pragma unroll
    for (int k = 0; k < 3; ++k) {
        int s = tid + BS_ * k;
        if (s < K_) {
            int w = s_perm[s];
            int v = w & 0xFFFF;
            int d = w >> 16;
            int base = s_binBase[d] + (s - s_binStart[d]) * d;
            pv[k] = v;
            od[k] = (unsigned)base | ((unsigned)d << 16);
            lr[k] = s_mem[v];
        } else { pv[k] = 0; od[k] = 0; lr[k] = 0.0f; }
    }
    float    t5[3];
    unsigned vnp[3][5];                  // slot | pos<<16
    #pragma unroll
    for (int kk = 0; kk < 3; ++kk) {
        int m = tid + BS_ * kk;
        if (m < M_) {
            #pragma unroll
            for (int j = 0; j < 5; ++j) {
                int v = edge_vn[m * ROW_ + j];
                int r = atomicAdd(&s_cnt[v], 1);
                int w = s_offslot[v];
                vnp[kk][j]  = (unsigned)(w >> 16) | ((unsigned)((w & 0xFFFF) + r) << 16);
            }
            float lrP = s_mem[K_ + m];
            float av  = __builtin_amdgcn_fmed3f(fabsf(lrP), AVLO_, AVHI_);
            float e   = exp2f(-av);
            float tm  = __fdividef(1.0f - e, 1.0f + e);
            t5[kk] = copysignf(tm, lrP);
        } else { t5[kk] = 0.0f; }
    }
    __syncthreads();
    // scratch fully consumed -> become the message array
    for (int i = tid; i < NIE_; i += BS_) s_mem[i] = 0.0f;
    __syncthreads();

    // ---- sum-product BP, flooding (all quantities in bits domain) ----
    for (int it = 0; it < NITER_; ++it) {
        // Phase A: slot-indexed marginals; paired reads -> ds_read2_b32
        #pragma unroll
        for (int k = 0; k < 3; ++k) {
            int s = tid + BS_ * k;
            if (s < K_) {
                int base = (int)(od[k] & 0xFFFFu);
                int dg   = (int)(od[k] >> 16);
                float mg = lr[k];
                int d = 0;
                for (; d + 1 < dg; d += 2) {
                    mg += s_mem[base + d];
                    mg += s_mem[base + d + 1];
                }
                if (d < dg) mg += s_mem[base + d];
                s_marg[s] = mg;
            }
        }
        __syncthreads();
        // Phase B: CN update; old c2v re-read from LDS (intra-thread
        // read-before-write, single writer per position)
        #pragma unroll
        for (int kk = 0; kk < 3; ++kk) {
            int m = tid + BS_ * kk;
            if (m < M_) {
                float tj[5];
                #pragma unroll
                for (int j = 0; j < 5; ++j) {
                    unsigned w = vnp[kk][j];
                    float v2c = s_marg[w & 0xFFFFu] - s_mem[w >> 16];
                    float av  = __builtin_amdgcn_fmed3f(fabsf(v2c), AVLO_, AVHI_);
                    float e   = exp2f(-av);
                    float tm  = __fdividef(1.0f - e, 1.0f + e);
                    tj[j] = copysignf(tm, v2c);
                }
                float qv[5];
                float pr = t5[kk];
                #pragma unroll
                for (int j = 0; j < 5; ++j) { qv[j] = pr; pr *= tj[j]; }
                float sf = 1.0f;
                #pragma unroll
                for (int j = 4; j >= 0; --j) { qv[j] *= sf; sf *= tj[j]; }
                #pragma unroll
                for (int j = 0; j < 5; ++j) {
                    float q = __builtin_amdgcn_fmed3f(qv[j], -QC_, QC_);
                    float r = log2f(__fdividef(1.0f + q, 1.0f - q));
                    s_mem[vnp[kk][j] >> 16] = r;
                }
            }
        }
        __syncthreads();
    }

    // ---- final marginal + hard decision on info VNs ----
    #pragma unroll
    for (int k = 0; k < 3; ++k) {
        int s = tid + BS_ * k;
        if (s < K_) {
            int base = (int)(od[k] & 0xFFFFu);
            int dg   = (int)(od[k] >> 16);
            float mg = lr[k];
            int d = 0;
            for (; d + 1 < dg; d += 2) {
                mg += s_mem[base + d];
                mg += s_mem[base + d + 1];
            }
            if (d < dg) mg += s_mem[base + d];
            out[(size_t)BATCH_ * K_ + b * K_ + pv[k]] = (mg < 0.0f) ? 1.0f : 0.0f;
        }
    }
}

extern "C" void kernel_launch(void* const* d_in, const int* in_sizes, int n_in,
                              void* d_out, int out_size, void* d_ws, size_t ws_size,
                              hipStream_t stream) {
    const int*   bits    = (const int*)  d_in[0];
    const int*   a_idx   = (const int*)  d_in[1];
    // d_in[2] = edge_cn (implicit: contiguous groups of 6) — unused
    const int*   edge_vn = (const int*)  d_in[3];
    const float* pre     = (const float*)d_in[4];
    const float* pim     = (const float*)d_in[5];
    const float* nre     = (const float*)d_in[6];
    const float* nim     = (const float*)d_in[7];
    const float* ebno    = (const float*)d_in[8];

    link_kernel<<<BATCH_, BS_, 0, stream>>>(bits, a_idx, pre, pim, nre, nim,
                                            ebno, edge_vn, (float*)d_out);
}

// Round 15
// 242.463 us; speedup vs baseline: 1.1284x; 1.0086x over previous
//
#include <hip/hip_runtime.h>

// Problem constants (match reference)
#define K_     1056
#define N_     2112
#define M_     1056   // N - K
#define E_     6336   // M * 6
#define NIE_   5280   // M * 5 info-side edges (the only BP state)
#define CAP_   6336   // padded c2v extent upper bound (stride = d|1 adds <=1/VN)
#define ALL_   7392   // CAP_ + K_ : c2v + marg unified array
#define DV_    5
#define ROW_   6      // edge 6m+5 is the parity VN K+m
#define NSYM_  528
#define NITER_ 20
#define BATCH_ 1024
#define BS_    512    // 8 waves/block -> 4 blocks/CU fills all 32 wave slots

#define LOG2E_ 1.4426950408889634f
#define AVLO_  (1e-6f * LOG2E_)          // |v2c| floor, bits units
#define AVHI_  (20.0f * LOG2E_)          // |v2c| cap,  bits units
#define QC_    0.99999988f               // tanh-domain cap (unchanged)

// stride(d) = d | 1 : even d -> d+1 (one pad slot), odd d -> d. Always ODD
// -> coprime with the 32 LDS banks -> Phase A's wave-uniform-stride segment
// reads are conflict-free. R13's compact layout (stride = d) showed
// SQ_LDS_BANK_CONFLICT 3.4e7 ~= 133K cycles/CU ~= 28% of the kernel; at 512
// threads the wave cap (4 blocks/CU) binds, so the padding's LDS cost
// (30 KB vs 26 KB) is free.
__device__ __forceinline__ int seg_stride(int d) { return d | 1; }

// -------------------------------------------------------------------------
// Single kernel, one block per codeword, 512 threads / 8 waves.
// Base-2 LLR domain after demap (LLR_hat = LLR * log2e): v_exp_f32 /
// v_log_f32 are natively 2^x / log2(x). Hard decisions scale-invariant.
//
// LDS (~30 KB): s_all[7392] unified —
//   build: [0..N) staging (bits -> LLR_hat), [N..N+4K) int scratch
//   BP:    [0..CAP) c2v odd-stride padded VN-major segments,
//          [CAP..7392) slot-indexed marginals (K floats)
//
// Structure exploited: H = [A | I].
//   * Parity VN (deg 1): v2c == channel LLR -> per-check constant t5.
//   * Info VNs counting-sorted by degree -> wave-uniform Phase A trips;
//     scan-free segment bases from 32-bin histogram arithmetic.
//   * Old c2v re-read from LDS (single writer per position) -> ~55 live
//     VGPRs in the hot loop.
//   * Atomic build order only permutes float accumulation order —
//     validated order-independent in R4-R13 (absmax 0).
//
// CN math (product form, prefix/suffix partial products, bits domain):
//   t = copysign((1-2^-av)/(1+2^-av), v2c);  q_j = t5 * prod_{i!=j} t_i
//   q = med3(q, -QC, QC);  r = log2((1+q)/(1-q))
// -------------------------------------------------------------------------
__global__ __launch_bounds__(BS_, 8) void link_kernel(
    const int*   __restrict__ bits,      // [B,K]
    const int*   __restrict__ a_idx,     // [M,DV]
    const float* __restrict__ points_re, // [16]
    const float* __restrict__ points_im, // [16]
    const float* __restrict__ noise_re,  // [B,NSYM]
    const float* __restrict__ noise_im,  // [B,NSYM]
    const float* __restrict__ ebno_db,   // [1]
    const int*   __restrict__ edge_vn,   // [E]
    float*       __restrict__ out)       // [2,B,K]
{
#pragma clang fp contract(off)
    const int b   = blockIdx.x;
    const int tid = threadIdx.x;

    __shared__ float s_all[ALL_];
    __shared__ float s_pre[16];
    __shared__ float s_pim[16];
    __shared__ int   s_hist[32];
    __shared__ int   s_binStart[32];
    __shared__ int   s_binBase[32];

    float* s_mem  = s_all;               // staging, later c2v [0..CAP)
    float* s_marg = s_all + CAP_;        // BP marginals [CAP..ALL)

    // build scratch aliases [N..N+4K) (inside s_all; demap uses [0..N))
    int* sc        = (int*)(s_all + N_);
    int* s_deg     = sc;                 // [K] degree
    int* s_perm    = sc + K_;            // [K] slot -> v | deg<<16
    int* s_offslot = sc + 2 * K_;        // [K] v -> base | slot<<16
    int* s_cnt     = sc + 3 * K_;        // [K] edge-fill cursors

    if (tid < 16) {
        s_pre[tid] = points_re[tid];
        s_pim[tid] = points_im[tid];
    }
    if (tid < 32) s_hist[tid] = 0;

    const float eb    = ebno_db[0];
    const float no    = 1.0f / ((powf(10.0f, eb / 10.0f) * 0.5f) * 4.0f);
    const float sigma = sqrtf(no / 2.0f);

    // ---- stage info bits (0/1 floats); output0 = bits.astype(f32) ----
    for (int i = tid; i < K_; i += BS_) {
        int v = bits[b * K_ + i];
        s_mem[i] = (float)v;
        out[b * K_ + i] = (float)v;
    }
    __syncthreads();

    // ---- parity: XOR of DV gathered info bits; zero build counters ----
    for (int m = tid; m < M_; m += BS_) {
        float acc = 0.0f;
        #pragma unroll
        for (int d = 0; d < DV_; ++d) acc += s_mem[a_idx[m * DV_ + d]];
        s_mem[K_ + m] = (float)(((int)acc) & 1);
    }
    for (int v = tid; v < K_; v += BS_) { s_deg[v] = 0; s_cnt[v] = 0; }
    __syncthreads();

    // ---- QAM + AWGN + exact APP demap (stores LLR * log2e) ----
    // ---- overlapped: VN degree count (disjoint LDS region)       ----
    for (int s = tid; s < NSYM_; s += BS_) {
        int c0 = (int)s_mem[4 * s + 0];
        int c1 = (int)s_mem[4 * s + 1];
        int c2 = (int)s_mem[4 * s + 2];
        int c3 = (int)s_mem[4 * s + 3];
        int sym = c0 * 8 + c1 * 4 + c2 * 2 + c3;
        float yre = s_pre[sym] + sigma * noise_re[b * NSYM_ + s];
        float yim = s_pim[sym] + sigma * noise_im[b * NSYM_ + s];
        float lg[16];
        #pragma unroll
        for (int p = 0; p < 16; ++p) {
            float dre  = yre - s_pre[p];
            float dim_ = yim - s_pim[p];
            float d2   = dre * dre + dim_ * dim_;
            lg[p] = -d2 / no;
        }
        float llr4[4];
        #pragma unroll
        for (int j = 0; j < 4; ++j) {
            float m0 = -1e30f, m1 = -1e30f;
            #pragma unroll
            for (int p = 0; p < 16; ++p) {
                if (((p >> (3 - j)) & 1) == 0) m0 = fmaxf(m0, lg[p]);
                else                           m1 = fmaxf(m1, lg[p]);
            }
            float sum0 = 0.0f, sum1 = 0.0f;
            #pragma unroll
            for (int p = 0; p < 16; ++p) {
                if (((p >> (3 - j)) & 1) == 0) sum0 += __expf(lg[p] - m0);
                else                           sum1 += __expf(lg[p] - m1);
            }
            llr4[j] = (m0 + __logf(sum0)) - (m1 + __logf(sum1));
        }
        s_mem[4 * s + 0] = llr4[0] * LOG2E_;
        s_mem[4 * s + 1] = llr4[1] * LOG2E_;
        s_mem[4 * s + 2] = llr4[2] * LOG2E_;
        s_mem[4 * s + 3] = llr4[3] * LOG2E_;
    }
    for (int idx = tid; idx < NIE_; idx += BS_) {
        int m = idx / 5, j = idx - m * 5;
        atomicAdd(&s_deg[edge_vn[m * ROW_ + j]], 1);
    }
    __syncthreads();

    // ---- degree histogram -> arithmetic segment bases (scan-free) ----
    for (int v = tid; v < K_; v += BS_) atomicAdd(&s_hist[s_deg[v] & 31], 1);
    __syncthreads();
    if (tid == 0) {
        int accS = 0, accB = 0;
        for (int d = 0; d < 32; ++d) {
            int c = s_hist[d];
            s_binStart[d] = accS;
            s_binBase[d]  = accB;
            s_hist[d]     = accS;        // reuse as sort cursor
            accS += c;
            accB += c * seg_stride(d);   // odd stride -> conflict-free
        }
    }
    __syncthreads();
    for (int v = tid; v < K_; v += BS_) {   // counting sort by degree
        int d    = s_deg[v];
        int slot = atomicAdd(&s_hist[d & 31], 1);
        int base = s_binBase[d] + (slot - s_binStart[d]) * seg_stride(d);
        s_perm[slot]  = v | (d << 16);
        s_offslot[v]  = base | (slot << 16);
    }
    __syncthreads();

    // ---- capture iteration-invariant state in registers ----
    int      pv[3];                      // slot -> VN id
    unsigned od[3];                      // base | deg<<16
    float    lr[3];                      // channel LLR_hat of owned VN
    #pragma unroll
    for (int k = 0; k < 3; ++k) {
        int s = tid + BS_ * k;
        if (s < K_) {
            int w = s_perm[s];
            int v = w & 0xFFFF;
            int d = w >> 16;
            int base = s_binBase[d] + (s - s_binStart[d]) * seg_stride(d);
            pv[k] = v;
            od[k] = (unsigned)base | ((unsigned)d << 16);
            lr[k] = s_mem[v];
        } else { pv[k] = 0; od[k] = 0; lr[k] = 0.0f; }
    }
    float    t5[3];
    unsigned vnp[3][5];                  // slot | pos<<16
    #pragma unroll
    for (int kk = 0; kk < 3; ++kk) {
        int m = tid + BS_ * kk;
        if (m < M_) {
            #pragma unroll
            for (int j = 0; j < 5; ++j) {
                int v = edge_vn[m * ROW_ + j];
                int r = atomicAdd(&s_cnt[v], 1);
                int w = s_offslot[v];
                vnp[kk][j]  = (unsigned)(w >> 16) | ((unsigned)((w & 0xFFFF) + r) << 16);
            }
            float lrP = s_mem[K_ + m];
            float av  = __builtin_amdgcn_fmed3f(fabsf(lrP), AVLO_, AVHI_);
            float e   = exp2f(-av);
            float tm  = __fdividef(1.0f - e, 1.0f + e);
            t5[kk] = copysignf(tm, lrP);
        } else { t5[kk] = 0.0f; }
    }
    __syncthreads();
    // scratch fully consumed -> become the message array
    for (int i = tid; i < CAP_; i += BS_) s_mem[i] = 0.0f;
    __syncthreads();

    // ---- sum-product BP, flooding (all quantities in bits domain) ----
    for (int it = 0; it < NITER_; ++it) {
        // Phase A: slot-indexed marginals; odd-stride segments -> no
        // structured bank conflicts; paired reads -> ds_read2_b32
        #pragma unroll
        for (int k = 0; k < 3; ++k) {
            int s = tid + BS_ * k;
            if (s < K_) {
                int base = (int)(od[k] & 0xFFFFu);
                int dg   = (int)(od[k] >> 16);
                float mg = lr[k];
                int d = 0;
                for (; d + 1 < dg; d += 2) {
                    mg += s_mem[base + d];
                    mg += s_mem[base + d + 1];
                }
                if (d < dg) mg += s_mem[base + d];
                s_marg[s] = mg;
            }
        }
        __syncthreads();
        // Phase B: CN update; old c2v re-read from LDS (intra-thread
        // read-before-write, single writer per position)
        #pragma unroll
        for (int kk = 0; kk < 3; ++kk) {
            int m = tid + BS_ * kk;
            if (m < M_) {
                float tj[5];
                #pragma unroll
                for (int j = 0; j < 5; ++j) {
                    unsigned w = vnp[kk][j];
                    float v2c = s_marg[w & 0xFFFFu] - s_mem[w >> 16];
                    float av  = __builtin_amdgcn_fmed3f(fabsf(v2c), AVLO_, AVHI_);
                    float e   = exp2f(-av);
                    float tm  = __fdividef(1.0f - e, 1.0f + e);
                    tj[j] = copysignf(tm, v2c);
                }
                float qv[5];
                float pr = t5[kk];
                #pragma unroll
                for (int j = 0; j < 5; ++j) { qv[j] = pr; pr *= tj[j]; }
                float sf = 1.0f;
                #pragma unroll
                for (int j = 4; j >= 0; --j) { qv[j] *= sf; sf *= tj[j]; }
                #pragma unroll
                for (int j = 0; j < 5; ++j) {
                    float q = __builtin_amdgcn_fmed3f(qv[j], -QC_, QC_);
                    float r = log2f(__fdividef(1.0f + q, 1.0f - q));
                    s_mem[vnp[kk][j] >> 16] = r;
                }
            }
        }
        __syncthreads();
    }

    // ---- final marginal + hard decision on info VNs ----
    #pragma unroll
    for (int k = 0; k < 3; ++k) {
        int s = tid + BS_ * k;
        if (s < K_) {
            int base = (int)(od[k] & 0xFFFFu);
            int dg   = (int)(od[k] >> 16);
            float mg = lr[k];
            int d = 0;
            for (; d + 1 < dg; d += 2) {
                mg += s_mem[base + d];
                mg += s_mem[base + d + 1];
            }
            if (d < dg) mg += s_mem[base + d];
            out[(size_t)BATCH_ * K_ + b * K_ + pv[k]] = (mg < 0.0f) ? 1.0f : 0.0f;
        }
    }
}

extern "C" void kernel_launch(void* const* d_in, const int* in_sizes, int n_in,
                              void* d_out, int out_size, void* d_ws, size_t ws_size,
                              hipStream_t stream) {
    const int*   bits    = (const int*)  d_in[0];
    const int*   a_idx   = (const int*)  d_in[1];
    // d_in[2] = edge_cn (implicit: contiguous groups of 6) — unused
    const int*   edge_vn = (const int*)  d_in[3];
    const float* pre     = (const float*)d_in[4];
    const float* pim     = (const float*)d_in[5];
    const float* nre     = (const float*)d_in[6];
    const float* nim     = (const float*)d_in[7];
    const float* ebno    = (const float*)d_in[8];

    link_kernel<<<BATCH_, BS_, 0, stream>>>(bits, a_idx, pre, pim, nre, nim,
                                            ebno, edge_vn, (float*)d_out);
}